// Round 11
// baseline (334.519 us; speedup 1.0000x reference)
//
#include <hip/hip_runtime.h>
#include <hip/hip_bf16.h>
#include <cstdint>

// ---------------------------------------------------------------------------
// GemResNetBlock: two gauge-equivariant convs + Fourier ReLU + linear residual
// Round-11: MFMA GEMM with batched B-frag loads + raised VGPR budget
// (round 10 was load-latency serialized at VGPR=60: compiler re-sank the 10
//  B-frag loads next to their MFMAs; 2740 cyc/chunk ≈ 13 serial L2 hits).
#define NV     20000
#define NE     160000
#define IC1    16
#define OC     32
#define DIN    5
#define NSLOT  49
#define NOUT   160              // (o,i) = 32*5
// ---------------------------------------------------------------------------
struct SlotTables {
    int n;
    int b[64], f[64], i[64], j[64];
    float v[64];
};

constexpr SlotTables make_slots() {
    SlotTables T{};
    float K[19][5][5][5] = {};   // [basis][freq][row i][col j]
    int nb = 0;
    const int BL = 2;
    auto add = [&](int f, const float (*cb)[2], const float (*sb)[2],
                   int m, int n) {
        if (f > BL) return;
        int r0 = (m == 0) ? 0 : (2 * m - 1), nr = (m == 0) ? 1 : 2;
        int c0 = (n == 0) ? 0 : (2 * n - 1), nc = (n == 0) ? 1 : 2;
        for (int a = 0; a < nr; a++)
            for (int bb = 0; bb < nc; bb++) {
                if (f == 0) {
                    K[nb][0][r0 + a][c0 + bb] = cb[a][bb];
                } else {
                    K[nb][2 * f - 1][r0 + a][c0 + bb] = cb[a][bb];
                    K[nb][2 * f    ][r0 + a][c0 + bb] = sb[a][bb];
                }
            }
        nb++;
    };
    const float ONE[2][2]  = {{1, 0}, {0, 0}};
    const float I2[2][2]   = {{1, 0}, {0, 1}};
    const float E2[2][2]   = {{0, -1}, {1, 0}};
    const float S2[2][2]   = {{1, 0}, {0, -1}};
    const float ES2[2][2]  = {{0, 1}, {1, 0}};
    const float NS2[2][2]  = {{-1, 0}, {0, 1}};
    const float C10[2][2]  = {{1, 0}, {0, 0}};
    const float C01[2][2]  = {{0, 0}, {1, 0}};
    const float CM10[2][2] = {{-1, 0}, {0, 0}};
    const float R10[2][2]  = {{1, 0}, {0, 0}};
    const float R01[2][2]  = {{0, 1}, {0, 0}};
    const float RM10[2][2] = {{-1, 0}, {0, 0}};

    for (int m = 0; m <= 2; m++)
        for (int n = 0; n <= 2; n++) {
            if (m == 0 && n == 0) {
                add(0, ONE, ONE, 0, 0);
            } else if (n == 0) {
                add(m, C10, C01, m, 0);
                add(m, C01, CM10, m, 0);
            } else if (m == 0) {
                add(n, R10, R01, 0, n);
                add(n, R01, RM10, 0, n);
            } else {
                int d = m - n;
                int f = d >= 0 ? d : -d;
                float sg = d >= 0 ? 1.f : -1.f;
                const float sgE[2][2]  = {{0, -sg}, {sg, 0}};
                const float msgI[2][2] = {{-sg, 0}, {0, -sg}};
                add(f, I2, sgE, m, n);
                add(f, E2, msgI, m, n);
                add(m + n, S2, ES2, m, n);
                add(m + n, ES2, NS2, m, n);
            }
        }
    T.n = 0;
    for (int i = 0; i < 5; i++)
        for (int b = 0; b < nb; b++)
            for (int f = 0; f < 5; f++)
                for (int j = 0; j < 5; j++)
                    if (K[b][f][i][j] != 0.0f) {
                        T.b[T.n] = b; T.f[T.n] = f; T.i[T.n] = i;
                        T.j[T.n] = j; T.v[T.n] = K[b][f][i][j];
                        T.n++;
                    }
    return T;
}

constexpr SlotTables SL = make_slots();
static_assert(SL.n == NSLOT, "expect 49 kernel-basis nonzeros");

__device__ __forceinline__ uint32_t bf16_rne(float f) {
    uint32_t u = __float_as_uint(f);
    u += 0x7fffu + ((u >> 16) & 1u);
    return u >> 16;
}

typedef __attribute__((ext_vector_type(8))) short bf16x8;   // MFMA A/B frag
typedef __attribute__((ext_vector_type(4))) float f32x4;    // MFMA C/D frag

// ---------------- M build: M[k][n], k=(c*50+j*10+q), n=(o*5+i) -------------
template<int C>
__global__ __launch_bounds__(256) void build_M(const float* __restrict__ W,
                                               float* __restrict__ M) {
    int t = blockIdx.x * 256 + threadIdx.x;
    const int K = C * 50;
    if (t >= K * NOUT) return;
    int n = t % NOUT, k = t / NOUT;
    int o = n / 5, i = n % 5;
    int c = k / 50, r50 = k % 50;
    int j = r50 / 10, q = r50 % 10;
    int f = q >> 1, r = q & 1;
    float acc = 0.f;
    #pragma unroll
    for (int s = 0; s < NSLOT; s++) {
        if (SL.j[s] == j && SL.f[s] == f && SL.i[s] == i)
            acc += SL.v[s] * W[(size_t)((SL.b[s] * 2 + r) * 32 + o) * C + c];
    }
    M[(size_t)k * NOUT + n] = acc;
}

// Swizzle M into MFMA B-fragment order (bf16):
// Mf[((ck*10+nt)*64+lane)*4+a] packs B[k0][col],B[k0+1][col]
// with k0 = ck*32 + (lane>>4)*8 + 2a, col = nt*16 + (lane&15).
template<int K>
__global__ __launch_bounds__(256) void build_Mfrag(const float* __restrict__ M,
                                                   uint32_t* __restrict__ Mf) {
    int t = blockIdx.x * 256 + threadIdx.x;
    const int total = (K / 32) * 10 * 64 * 4;
    if (t >= total) return;
    int a = t & 3;
    int idx = t >> 2;
    int lane = idx & 63; idx >>= 6;
    int nt = idx % 10;
    int ck = idx / 10;
    int col = nt * 16 + (lane & 15);
    int k0 = ck * 32 + (lane >> 4) * 8 + 2 * a;
    uint32_t lo = bf16_rne(M[(size_t)k0 * NOUT + col]);
    uint32_t hi = bf16_rne(M[(size_t)(k0 + 1) * NOUT + col]);
    Mf[t] = lo | (hi << 16);
}

// ---------------- CSR build ------------------------------------------------
__global__ __launch_bounds__(256) void hist_k(const int* __restrict__ ei,
                                              int* __restrict__ counts) {
    int e = blockIdx.x * 256 + threadIdx.x;
    if (e < NE) atomicAdd(&counts[ei[e]], 1);   // ei[e] = dst
}

__global__ __launch_bounds__(1024) void scan_k(const int* __restrict__ counts,
                                               int* __restrict__ cursor) {
    __shared__ int part[1024];
    int t = threadIdx.x;
    int base = t * 20;
    int local[20];
    int s = 0;
    #pragma unroll
    for (int k = 0; k < 20; k++) {
        int idx = base + k;
        int c = (idx < NV) ? counts[idx] : 0;
        local[k] = c; s += c;
    }
    part[t] = s;
    __syncthreads();
    for (int off = 1; off < 1024; off <<= 1) {
        int add = (t >= off) ? part[t - off] : 0;
        __syncthreads();
        part[t] += add;
        __syncthreads();
    }
    int run = (t == 0) ? 0 : part[t - 1];
    #pragma unroll
    for (int k = 0; k < 20; k++) {
        int idx = base + k;
        if (idx < NV) { cursor[idx] = run; run += local[k]; }
    }
}

__global__ __launch_bounds__(256) void scatter_k(const int* __restrict__ ei,
                                                 int* __restrict__ cursor,
                                                 int* __restrict__ order) {
    int e = blockIdx.x * 256 + threadIdx.x;
    if (e >= NE) return;
    int pos = atomicAdd(&cursor[ei[e]], 1);
    order[pos] = e;
}

// ---------------- Z build: thread (v,c) -> 50 bf16 (25 packed uints) -------
template<int C>
__global__ __launch_bounds__(256) void zbuild(const float* __restrict__ xin,
                                              const int*   __restrict__ ei,
                                              const float* __restrict__ pre,
                                              const float* __restrict__ conn,
                                              const int* __restrict__ cursor,
                                              const int* __restrict__ order,
                                              uint32_t* __restrict__ Z,
                                              int v0, int v1) {
    int t = blockIdx.x * 256 + threadIdx.x;
    int rows = (v1 - v0) * C;
    if (t >= rows) return;
    int c = t % C;
    int v = v0 + t / C;
    int beg = (v == 0) ? 0 : cursor[v - 1];
    int end = cursor[v];
    float acc[50];
    #pragma unroll
    for (int z = 0; z < 50; z++) acc[z] = 0.f;

    for (int k = beg; k < end; k++) {
        int e = order[k];
        int src = ei[NE + e];
        float al = conn[e];
        float c1 = __cosf(al), s1 = __sinf(al);
        float c2 = c1 * c1 - s1 * s1, s2 = 2.0f * c1 * s1;
        float p[10];
        #pragma unroll
        for (int q = 0; q < 10; q++) p[q] = pre[(size_t)e * 10 + q];
        const float* xb = xin + ((size_t)src * C + c) * DIN;
        float x0 = xb[0], x1 = xb[1], x2 = xb[2], x3 = xb[3], x4 = xb[4];
        float xt[5];
        xt[0] = x0;
        xt[1] = c1 * x1 - s1 * x2;
        xt[2] = s1 * x1 + c1 * x2;
        xt[3] = c2 * x3 - s2 * x4;
        xt[4] = s2 * x3 + c2 * x4;
        #pragma unroll
        for (int j = 0; j < 5; j++)
            #pragma unroll
            for (int q = 0; q < 10; q++)
                acc[j * 10 + q] = fmaf(xt[j], p[q], acc[j * 10 + q]);
    }
    uint32_t* zb = Z + (size_t)t * 25;   // row t = (v-v0)*C + c, 50 bf16
    #pragma unroll
    for (int z = 0; z < 25; z++)
        zb[z] = bf16_rne(acc[2 * z]) | (bf16_rne(acc[2 * z + 1]) << 16);
}

// ---------------- MFMA GEMM: Y[v,n] = sum_k Z[v,k]*M[k,n] ------------------
// 4 waves/block, each wave: 16-row tile x all 160 cols (10 acc frags).
// Per 32-k chunk: 1 A-frag + 10 B-frags loaded as an explicit BATCH into
// bf[10] (independent, issued back-to-back), then 10 MFMAs consume.
// __launch_bounds__(256,4) caps VGPR at 128 so the batch is NOT re-sunk
// (round 10 at default budget: VGPR=60, loads serialized, 2740 cyc/chunk).
template<int K>
__global__ __launch_bounds__(256, 4) void gemm_mfma(const uint32_t* __restrict__ Z,
                                                    const uint32_t* __restrict__ Mf,
                                                    float* __restrict__ Y,
                                                    int rows) {
    int t = threadIdx.x;
    int lane = t & 63;
    int wave = t >> 6;
    int r0 = blockIdx.x * 64 + wave * 16;
    int mrow = lane & 15;
    int q = lane >> 4;
    int ra = r0 + mrow;
    if (ra >= rows) ra = rows - 1;          // clamp A loads; store masked
    const uint32_t* za = Z + (size_t)ra * (K / 2) + q * 4;
    const bf16x8* mf = (const bf16x8*)Mf;

    f32x4 acc[10];
    #pragma unroll
    for (int nt = 0; nt < 10; nt++) acc[nt] = {0.f, 0.f, 0.f, 0.f};

    #pragma unroll 2
    for (int ck = 0; ck < K / 32; ck++) {
        const bf16x8* mrow_f = mf + (size_t)(ck * 10) * 64 + lane;
        bf16x8 af = *(const bf16x8*)(za + ck * 16);
        bf16x8 bf[10];
        #pragma unroll
        for (int nt = 0; nt < 10; nt++) bf[nt] = mrow_f[nt * 64];
        #pragma unroll
        for (int nt = 0; nt < 10; nt++)
            acc[nt] = __builtin_amdgcn_mfma_f32_16x16x32_bf16(af, bf[nt],
                                                              acc[nt], 0, 0, 0);
    }
    // C/D layout: col = lane&15, row = q*4 + reg  [verified m89/m91]
    #pragma unroll
    for (int reg = 0; reg < 4; reg++) {
        int rr = r0 + q * 4 + reg;
        if (rr < rows) {
            float* yb = Y + (size_t)rr * NOUT + (lane & 15);
            #pragma unroll
            for (int nt = 0; nt < 10; nt++) yb[nt * 16] = acc[nt][reg];
        }
    }
}

// ---------------- Fourier ReLU + epilogues ---------------------------------
__device__ __forceinline__ void fourier_relu(float d0, float d1, float d2,
                                             float d3, float d4, float* out5) {
    float o0 = 0, o1 = 0, o2 = 0, o3 = 0, o4 = 0;
    #pragma unroll
    for (int k = 0; k < 7; k++) {
        float th = (float)k * (6.28318530717958647692f / 7.0f);
        float ck = __cosf(th), sk = __sinf(th);
        float c2k = ck * ck - sk * sk, s2k = 2.f * ck * sk;
        float sv = d0 + ck * d1 + sk * d2 + c2k * d3 + s2k * d4;
        sv = fmaxf(sv, 0.f);
        o0 += sv; o1 += sv * ck; o2 += sv * sk; o3 += sv * c2k; o4 += sv * s2k;
    }
    const float i7 = 1.0f / 7.0f;
    out5[0] = o0 * i7; out5[1] = o1 * (2.f * i7); out5[2] = o2 * (2.f * i7);
    out5[3] = o3 * (2.f * i7); out5[4] = o4 * (2.f * i7);
}

__global__ __launch_bounds__(256) void relu_mid(float* __restrict__ y,
                                                const float* __restrict__ b1) {
    int t = blockIdx.x * 256 + threadIdx.x;     // v*32 + ch
    if (t >= NV * 32) return;
    int ch = t & 31;
    float* yb = y + (size_t)t * 5;
    float r[5];
    fourier_relu(yb[0] + b1[ch], yb[1], yb[2], yb[3], yb[4], r);
    #pragma unroll
    for (int d = 0; d < 5; d++) yb[d] = r[d];
}

__global__ __launch_bounds__(256) void final_k(const float* __restrict__ y2,
                                               const float* __restrict__ x,
                                               const float* __restrict__ Wl,
                                               const float* __restrict__ bl,
                                               const float* __restrict__ b2,
                                               float* __restrict__ out) {
    int t = blockIdx.x * 256 + threadIdx.x;     // v*32 + o
    if (t >= NV * 32) return;
    int o = t & 31;
    int v = t >> 5;
    float r0 = 0, r1 = 0, r2 = 0, r3 = 0, r4 = 0;
    const float* xb = x + (size_t)v * (IC1 * DIN);
    const float* wl = Wl + o * IC1;
    #pragma unroll
    for (int c = 0; c < IC1; c++) {
        float w = wl[c];
        r0 = fmaf(w, xb[c*5+0], r0); r1 = fmaf(w, xb[c*5+1], r1);
        r2 = fmaf(w, xb[c*5+2], r2); r3 = fmaf(w, xb[c*5+3], r3);
        r4 = fmaf(w, xb[c*5+4], r4);
    }
    float blo = bl[o];
    const float* yb = y2 + (size_t)t * 5;
    float d0 = yb[0] + b2[o] + r0 + blo;
    float d1 = yb[1] + r1 + blo;
    float d2 = yb[2] + r2 + blo;
    float d3 = yb[3] + r3 + blo;
    float d4 = yb[4] + r4 + blo;
    float r[5];
    fourier_relu(d0, d1, d2, d3, d4, r);
    float* ob = out + (size_t)t * 5;
    #pragma unroll
    for (int d = 0; d < 5; d++) ob[d] = r[d];
}

extern "C" void kernel_launch(void* const* d_in, const int* in_sizes, int n_in,
                              void* d_out, int out_size, void* d_ws, size_t ws_size,
                              hipStream_t stream) {
    const float* x    = (const float*)d_in[0];
    const int*   ei   = (const int*)  d_in[1];
    const float* pre  = (const float*)d_in[2];
    const float* conn = (const float*)d_in[3];
    const float* W1   = (const float*)d_in[4];
    const float* b1   = (const float*)d_in[5];
    const float* W2   = (const float*)d_in[6];
    const float* b2   = (const float*)d_in[7];
    const float* Wl   = (const float*)d_in[8];
    const float* bl   = (const float*)d_in[9];
    float* out = (float*)d_out;

    const int K1 = IC1 * 50;   // 800
    const int K2 = OC  * 50;   // 1600

    // ws layout: y1 | y2 | M1 | M2 | Mf1 | Mf2 | csr | Ztail
    const size_t Y_BYTES   = (size_t)NV * NOUT * sizeof(float);     // 12.8 MB
    const size_t M1_BYTES  = (size_t)K1 * NOUT * sizeof(float);     // 512 KB
    const size_t M2_BYTES  = (size_t)K2 * NOUT * sizeof(float);     // 1 MB
    const size_t MF1_BYTES = (size_t)(K1 / 32) * 10 * 64 * 16;      // 256 KB
    const size_t MF2_BYTES = (size_t)(K2 / 32) * 10 * 64 * 16;      // 512 KB
    const size_t CSR_BYTES = (size_t)(2 * NV + NE) * sizeof(int);   // 800 KB
    char* ws = (char*)d_ws;
    float* y1 = (float*)(ws);
    float* y2 = (float*)(ws + Y_BYTES);
    float* M1 = (float*)(ws + 2 * Y_BYTES);
    float* M2 = (float*)(ws + 2 * Y_BYTES + M1_BYTES);
    uint32_t* Mf1 = (uint32_t*)(ws + 2 * Y_BYTES + M1_BYTES + M2_BYTES);
    uint32_t* Mf2 = (uint32_t*)(ws + 2 * Y_BYTES + M1_BYTES + M2_BYTES + MF1_BYTES);
    int* counts = (int*)(ws + 2 * Y_BYTES + M1_BYTES + M2_BYTES + MF1_BYTES + MF2_BYTES);
    int* cursor = counts + NV;
    int* order  = cursor + NV;
    size_t fixed = 2 * Y_BYTES + M1_BYTES + M2_BYTES + MF1_BYTES + MF2_BYTES
                 + CSR_BYTES;

    // Z buffer (bf16): ws tail if it has room, else d_out (dead until final_k)
    size_t tail = (ws_size > fixed) ? (ws_size - fixed) : 0;
    uint32_t* zbuf;
    size_t zcap;
    if (tail >= Y_BYTES) { zbuf = (uint32_t*)(ws + fixed); zcap = tail; }
    else                 { zbuf = (uint32_t*)d_out;        zcap = Y_BYTES; }
    int chunk1 = (int)(zcap / ((size_t)K1 * 2)); if (chunk1 > NV) chunk1 = NV;
    int chunk2 = (int)(zcap / ((size_t)K2 * 2)); if (chunk2 > NV) chunk2 = NV;

    hipMemsetAsync(counts, 0, NV * sizeof(int), stream);

    build_M<IC1><<<(K1 * NOUT + 255) / 256, 256, 0, stream>>>(W1, M1);
    build_M<OC> <<<(K2 * NOUT + 255) / 256, 256, 0, stream>>>(W2, M2);
    build_Mfrag<K1><<<((K1 / 32) * 2560 + 255) / 256, 256, 0, stream>>>(M1, Mf1);
    build_Mfrag<K2><<<((K2 / 32) * 2560 + 255) / 256, 256, 0, stream>>>(M2, Mf2);

    hist_k   <<<(NE + 255) / 256, 256, 0, stream>>>(ei, counts);
    scan_k   <<<1, 1024, 0, stream>>>(counts, cursor);
    scatter_k<<<(NE + 255) / 256, 256, 0, stream>>>(ei, cursor, order);

    // layer 1
    for (int v0 = 0; v0 < NV; v0 += chunk1) {
        int v1 = v0 + chunk1; if (v1 > NV) v1 = NV;
        int rows = v1 - v0;
        zbuild<IC1><<<(rows * IC1 + 255) / 256, 256, 0, stream>>>(
            x, ei, pre, conn, cursor, order, zbuf, v0, v1);
        gemm_mfma<K1><<<(rows + 63) / 64, 256, 0, stream>>>(
            zbuf, Mf1, y1 + (size_t)v0 * NOUT, rows);
    }
    relu_mid<<<(NV * 32 + 255) / 256, 256, 0, stream>>>(y1, b1);
    // layer 2
    for (int v0 = 0; v0 < NV; v0 += chunk2) {
        int v1 = v0 + chunk2; if (v1 > NV) v1 = NV;
        int rows = v1 - v0;
        zbuild<OC><<<(rows * OC + 255) / 256, 256, 0, stream>>>(
            y1, ei, pre, conn, cursor, order, zbuf, v0, v1);
        gemm_mfma<K2><<<(rows + 63) / 64, 256, 0, stream>>>(
            zbuf, Mf2, y2 + (size_t)v0 * NOUT, rows);
    }
    final_k<<<(NV * 32 + 255) / 256, 256, 0, stream>>>(y2, x, Wl, bl, b2, out);
}

// Round 12
// 279.978 us; speedup vs baseline: 1.1948x; 1.1948x over previous
//
#include <hip/hip_runtime.h>
#include <hip/hip_bf16.h>
#include <cstdint>

// ---------------------------------------------------------------------------
// GemResNetBlock: two gauge-equivariant convs + Fourier ReLU + linear residual
// Round-12: MFMA GEMM with double-buffered LDS B-tiles via async DMA
// (global_load_lds).  Rounds 10/11 proved register-staged batches get re-sunk
// by the scheduler (load->mfma serial, ~200cyc/load); DMA->LDS cannot be.
#define NV     20000
#define NE     160000
#define IC1    16
#define OC     32
#define DIN    5
#define NSLOT  49
#define NOUT   160              // (o,i) = 32*5
// ---------------------------------------------------------------------------
struct SlotTables {
    int n;
    int b[64], f[64], i[64], j[64];
    float v[64];
};

constexpr SlotTables make_slots() {
    SlotTables T{};
    float K[19][5][5][5] = {};   // [basis][freq][row i][col j]
    int nb = 0;
    const int BL = 2;
    auto add = [&](int f, const float (*cb)[2], const float (*sb)[2],
                   int m, int n) {
        if (f > BL) return;
        int r0 = (m == 0) ? 0 : (2 * m - 1), nr = (m == 0) ? 1 : 2;
        int c0 = (n == 0) ? 0 : (2 * n - 1), nc = (n == 0) ? 1 : 2;
        for (int a = 0; a < nr; a++)
            for (int bb = 0; bb < nc; bb++) {
                if (f == 0) {
                    K[nb][0][r0 + a][c0 + bb] = cb[a][bb];
                } else {
                    K[nb][2 * f - 1][r0 + a][c0 + bb] = cb[a][bb];
                    K[nb][2 * f    ][r0 + a][c0 + bb] = sb[a][bb];
                }
            }
        nb++;
    };
    const float ONE[2][2]  = {{1, 0}, {0, 0}};
    const float I2[2][2]   = {{1, 0}, {0, 1}};
    const float E2[2][2]   = {{0, -1}, {1, 0}};
    const float S2[2][2]   = {{1, 0}, {0, -1}};
    const float ES2[2][2]  = {{0, 1}, {1, 0}};
    const float NS2[2][2]  = {{-1, 0}, {0, 1}};
    const float C10[2][2]  = {{1, 0}, {0, 0}};
    const float C01[2][2]  = {{0, 0}, {1, 0}};
    const float CM10[2][2] = {{-1, 0}, {0, 0}};
    const float R10[2][2]  = {{1, 0}, {0, 0}};
    const float R01[2][2]  = {{0, 1}, {0, 0}};
    const float RM10[2][2] = {{-1, 0}, {0, 0}};

    for (int m = 0; m <= 2; m++)
        for (int n = 0; n <= 2; n++) {
            if (m == 0 && n == 0) {
                add(0, ONE, ONE, 0, 0);
            } else if (n == 0) {
                add(m, C10, C01, m, 0);
                add(m, C01, CM10, m, 0);
            } else if (m == 0) {
                add(n, R10, R01, 0, n);
                add(n, R01, RM10, 0, n);
            } else {
                int d = m - n;
                int f = d >= 0 ? d : -d;
                float sg = d >= 0 ? 1.f : -1.f;
                const float sgE[2][2]  = {{0, -sg}, {sg, 0}};
                const float msgI[2][2] = {{-sg, 0}, {0, -sg}};
                add(f, I2, sgE, m, n);
                add(f, E2, msgI, m, n);
                add(m + n, S2, ES2, m, n);
                add(m + n, ES2, NS2, m, n);
            }
        }
    T.n = 0;
    for (int i = 0; i < 5; i++)
        for (int b = 0; b < nb; b++)
            for (int f = 0; f < 5; f++)
                for (int j = 0; j < 5; j++)
                    if (K[b][f][i][j] != 0.0f) {
                        T.b[T.n] = b; T.f[T.n] = f; T.i[T.n] = i;
                        T.j[T.n] = j; T.v[T.n] = K[b][f][i][j];
                        T.n++;
                    }
    return T;
}

constexpr SlotTables SL = make_slots();
static_assert(SL.n == NSLOT, "expect 49 kernel-basis nonzeros");

__device__ __forceinline__ uint32_t bf16_rne(float f) {
    uint32_t u = __float_as_uint(f);
    u += 0x7fffu + ((u >> 16) & 1u);
    return u >> 16;
}

typedef __attribute__((ext_vector_type(8))) short bf16x8;   // MFMA A/B frag
typedef __attribute__((ext_vector_type(4))) float f32x4;    // MFMA C/D frag

// ---------------- M build: M[k][n], k=(c*50+j*10+q), n=(o*5+i) -------------
template<int C>
__global__ __launch_bounds__(256) void build_M(const float* __restrict__ W,
                                               float* __restrict__ M) {
    int t = blockIdx.x * 256 + threadIdx.x;
    const int K = C * 50;
    if (t >= K * NOUT) return;
    int n = t % NOUT, k = t / NOUT;
    int o = n / 5, i = n % 5;
    int c = k / 50, r50 = k % 50;
    int j = r50 / 10, q = r50 % 10;
    int f = q >> 1, r = q & 1;
    float acc = 0.f;
    #pragma unroll
    for (int s = 0; s < NSLOT; s++) {
        if (SL.j[s] == j && SL.f[s] == f && SL.i[s] == i)
            acc += SL.v[s] * W[(size_t)((SL.b[s] * 2 + r) * 32 + o) * C + c];
    }
    M[(size_t)k * NOUT + n] = acc;
}

// Swizzle M into MFMA B-fragment order (bf16):
// Mf[((ck*10+nt)*64+lane)*4+a] packs B[k0][col],B[k0+1][col]
// with k0 = ck*32 + (lane>>4)*8 + 2a, col = nt*16 + (lane&15).
template<int K>
__global__ __launch_bounds__(256) void build_Mfrag(const float* __restrict__ M,
                                                   uint32_t* __restrict__ Mf) {
    int t = blockIdx.x * 256 + threadIdx.x;
    const int total = (K / 32) * 10 * 64 * 4;
    if (t >= total) return;
    int a = t & 3;
    int idx = t >> 2;
    int lane = idx & 63; idx >>= 6;
    int nt = idx % 10;
    int ck = idx / 10;
    int col = nt * 16 + (lane & 15);
    int k0 = ck * 32 + (lane >> 4) * 8 + 2 * a;
    uint32_t lo = bf16_rne(M[(size_t)k0 * NOUT + col]);
    uint32_t hi = bf16_rne(M[(size_t)(k0 + 1) * NOUT + col]);
    Mf[t] = lo | (hi << 16);
}

// ---------------- CSR build ------------------------------------------------
__global__ __launch_bounds__(256) void hist_k(const int* __restrict__ ei,
                                              int* __restrict__ counts) {
    int e = blockIdx.x * 256 + threadIdx.x;
    if (e < NE) atomicAdd(&counts[ei[e]], 1);   // ei[e] = dst
}

__global__ __launch_bounds__(1024) void scan_k(const int* __restrict__ counts,
                                               int* __restrict__ cursor) {
    __shared__ int part[1024];
    int t = threadIdx.x;
    int base = t * 20;
    int local[20];
    int s = 0;
    #pragma unroll
    for (int k = 0; k < 20; k++) {
        int idx = base + k;
        int c = (idx < NV) ? counts[idx] : 0;
        local[k] = c; s += c;
    }
    part[t] = s;
    __syncthreads();
    for (int off = 1; off < 1024; off <<= 1) {
        int add = (t >= off) ? part[t - off] : 0;
        __syncthreads();
        part[t] += add;
        __syncthreads();
    }
    int run = (t == 0) ? 0 : part[t - 1];
    #pragma unroll
    for (int k = 0; k < 20; k++) {
        int idx = base + k;
        if (idx < NV) { cursor[idx] = run; run += local[k]; }
    }
}

__global__ __launch_bounds__(256) void scatter_k(const int* __restrict__ ei,
                                                 int* __restrict__ cursor,
                                                 int* __restrict__ order) {
    int e = blockIdx.x * 256 + threadIdx.x;
    if (e >= NE) return;
    int pos = atomicAdd(&cursor[ei[e]], 1);
    order[pos] = e;
}

// ---------------- Z build: thread (v,c) -> 50 bf16 (25 packed uints) -------
template<int C>
__global__ __launch_bounds__(256) void zbuild(const float* __restrict__ xin,
                                              const int*   __restrict__ ei,
                                              const float* __restrict__ pre,
                                              const float* __restrict__ conn,
                                              const int* __restrict__ cursor,
                                              const int* __restrict__ order,
                                              uint32_t* __restrict__ Z,
                                              int v0, int v1) {
    int t = blockIdx.x * 256 + threadIdx.x;
    int rows = (v1 - v0) * C;
    if (t >= rows) return;
    int c = t % C;
    int v = v0 + t / C;
    int beg = (v == 0) ? 0 : cursor[v - 1];
    int end = cursor[v];
    float acc[50];
    #pragma unroll
    for (int z = 0; z < 50; z++) acc[z] = 0.f;

    for (int k = beg; k < end; k++) {
        int e = order[k];
        int src = ei[NE + e];
        float al = conn[e];
        float c1 = __cosf(al), s1 = __sinf(al);
        float c2 = c1 * c1 - s1 * s1, s2 = 2.0f * c1 * s1;
        float p[10];
        #pragma unroll
        for (int q = 0; q < 10; q++) p[q] = pre[(size_t)e * 10 + q];
        const float* xb = xin + ((size_t)src * C + c) * DIN;
        float x0 = xb[0], x1 = xb[1], x2 = xb[2], x3 = xb[3], x4 = xb[4];
        float xt[5];
        xt[0] = x0;
        xt[1] = c1 * x1 - s1 * x2;
        xt[2] = s1 * x1 + c1 * x2;
        xt[3] = c2 * x3 - s2 * x4;
        xt[4] = s2 * x3 + c2 * x4;
        #pragma unroll
        for (int j = 0; j < 5; j++)
            #pragma unroll
            for (int q = 0; q < 10; q++)
                acc[j * 10 + q] = fmaf(xt[j], p[q], acc[j * 10 + q]);
    }
    uint32_t* zb = Z + (size_t)t * 25;   // row t = (v-v0)*C + c, 50 bf16
    #pragma unroll
    for (int z = 0; z < 25; z++)
        zb[z] = bf16_rne(acc[2 * z]) | (bf16_rne(acc[2 * z + 1]) << 16);
}

// ---------------- MFMA GEMM: Y[v,n] = sum_k Z[v,k]*M[k,n] ------------------
// 4 waves/block, 64 rows/block, all 160 cols.  B-frags (identical for the 4
// waves) live in double-buffered LDS, filled by async DMA (global_load_lds,
// width 16): per chunk, stage chunk ck+1 into Bs[buf^1] BEFORE computing ck,
// prefetch A one chunk ahead in regs, one __syncthreads per chunk (its
// implicit vmcnt(0) drain lands after the whole compute phase).
template<int K>
__global__ __launch_bounds__(256) void gemm_mfma(const uint32_t* __restrict__ Z,
                                                 const uint32_t* __restrict__ Mf,
                                                 float* __restrict__ Y,
                                                 int rows) {
    constexpr int NC = K / 32;
    __shared__ uint4 Bs[2][640];        // 2 x 10 KB
    int t = threadIdx.x;
    int lane = t & 63;
    int wave = t >> 6;
    int r0 = blockIdx.x * 64 + wave * 16;
    int mrow = lane & 15;
    int q = lane >> 4;
    int ra = r0 + mrow;
    if (ra >= rows) ra = rows - 1;          // clamp A loads; store masked
    const uint32_t* za = Z + (size_t)ra * (K / 2) + q * 4;
    const uint4* mfg = (const uint4*)Mf + lane;

    // stage chunk ck into LDS buffer nb (each wave issues its i-subset; LDS
    // dst is wave-uniform base + lane*16, matching the DMA constraint)
    auto stage = [&](int ck, int nb) {
        const uint4* gp = mfg + (size_t)ck * 640;
        for (int i = wave; i < 10; i += 4)
            __builtin_amdgcn_global_load_lds(
                (const __attribute__((address_space(1))) void*)(gp + i * 64),
                (__attribute__((address_space(3))) void*)(&Bs[nb][i * 64]),
                16, 0, 0);
    };

    f32x4 acc[10];
    #pragma unroll
    for (int nt = 0; nt < 10; nt++) acc[nt] = {0.f, 0.f, 0.f, 0.f};

    stage(0, 0);
    bf16x8 af = *(const bf16x8*)za;         // A chunk 0 (overlaps DMA wait)
    __syncthreads();

    for (int ck = 0; ck < NC; ck++) {
        int buf = ck & 1;
        bf16x8 af_n = af;
        if (ck + 1 < NC) {
            stage(ck + 1, buf ^ 1);         // async DMA, consumed next iter
            af_n = *(const bf16x8*)(za + (ck + 1) * 16);
        }
        bf16x8 bf[10];
        #pragma unroll
        for (int nt = 0; nt < 10; nt++)
            bf[nt] = *(const bf16x8*)&Bs[buf][nt * 64 + lane];
        #pragma unroll
        for (int nt = 0; nt < 10; nt++)
            acc[nt] = __builtin_amdgcn_mfma_f32_16x16x32_bf16(af, bf[nt],
                                                              acc[nt], 0, 0, 0);
        af = af_n;
        __syncthreads();                    // drain DMA + protect Bs[buf]
    }
    // C/D layout: col = lane&15, row = q*4 + reg  [verified m89/m91]
    #pragma unroll
    for (int reg = 0; reg < 4; reg++) {
        int rr = r0 + q * 4 + reg;
        if (rr < rows) {
            float* yb = Y + (size_t)rr * NOUT + (lane & 15);
            #pragma unroll
            for (int nt = 0; nt < 10; nt++) yb[nt * 16] = acc[nt][reg];
        }
    }
}

// ---------------- Fourier ReLU + epilogues ---------------------------------
__device__ __forceinline__ void fourier_relu(float d0, float d1, float d2,
                                             float d3, float d4, float* out5) {
    float o0 = 0, o1 = 0, o2 = 0, o3 = 0, o4 = 0;
    #pragma unroll
    for (int k = 0; k < 7; k++) {
        float th = (float)k * (6.28318530717958647692f / 7.0f);
        float ck = __cosf(th), sk = __sinf(th);
        float c2k = ck * ck - sk * sk, s2k = 2.f * ck * sk;
        float sv = d0 + ck * d1 + sk * d2 + c2k * d3 + s2k * d4;
        sv = fmaxf(sv, 0.f);
        o0 += sv; o1 += sv * ck; o2 += sv * sk; o3 += sv * c2k; o4 += sv * s2k;
    }
    const float i7 = 1.0f / 7.0f;
    out5[0] = o0 * i7; out5[1] = o1 * (2.f * i7); out5[2] = o2 * (2.f * i7);
    out5[3] = o3 * (2.f * i7); out5[4] = o4 * (2.f * i7);
}

__global__ __launch_bounds__(256) void relu_mid(float* __restrict__ y,
                                                const float* __restrict__ b1) {
    int t = blockIdx.x * 256 + threadIdx.x;     // v*32 + ch
    if (t >= NV * 32) return;
    int ch = t & 31;
    float* yb = y + (size_t)t * 5;
    float r[5];
    fourier_relu(yb[0] + b1[ch], yb[1], yb[2], yb[3], yb[4], r);
    #pragma unroll
    for (int d = 0; d < 5; d++) yb[d] = r[d];
}

__global__ __launch_bounds__(256) void final_k(const float* __restrict__ y2,
                                               const float* __restrict__ x,
                                               const float* __restrict__ Wl,
                                               const float* __restrict__ bl,
                                               const float* __restrict__ b2,
                                               float* __restrict__ out) {
    int t = blockIdx.x * 256 + threadIdx.x;     // v*32 + o
    if (t >= NV * 32) return;
    int o = t & 31;
    int v = t >> 5;
    float r0 = 0, r1 = 0, r2 = 0, r3 = 0, r4 = 0;
    const float* xb = x + (size_t)v * (IC1 * DIN);
    const float* wl = Wl + o * IC1;
    #pragma unroll
    for (int c = 0; c < IC1; c++) {
        float w = wl[c];
        r0 = fmaf(w, xb[c*5+0], r0); r1 = fmaf(w, xb[c*5+1], r1);
        r2 = fmaf(w, xb[c*5+2], r2); r3 = fmaf(w, xb[c*5+3], r3);
        r4 = fmaf(w, xb[c*5+4], r4);
    }
    float blo = bl[o];
    const float* yb = y2 + (size_t)t * 5;
    float d0 = yb[0] + b2[o] + r0 + blo;
    float d1 = yb[1] + r1 + blo;
    float d2 = yb[2] + r2 + blo;
    float d3 = yb[3] + r3 + blo;
    float d4 = yb[4] + r4 + blo;
    float r[5];
    fourier_relu(d0, d1, d2, d3, d4, r);
    float* ob = out + (size_t)t * 5;
    #pragma unroll
    for (int d = 0; d < 5; d++) ob[d] = r[d];
}

extern "C" void kernel_launch(void* const* d_in, const int* in_sizes, int n_in,
                              void* d_out, int out_size, void* d_ws, size_t ws_size,
                              hipStream_t stream) {
    const float* x    = (const float*)d_in[0];
    const int*   ei   = (const int*)  d_in[1];
    const float* pre  = (const float*)d_in[2];
    const float* conn = (const float*)d_in[3];
    const float* W1   = (const float*)d_in[4];
    const float* b1   = (const float*)d_in[5];
    const float* W2   = (const float*)d_in[6];
    const float* b2   = (const float*)d_in[7];
    const float* Wl   = (const float*)d_in[8];
    const float* bl   = (const float*)d_in[9];
    float* out = (float*)d_out;

    const int K1 = IC1 * 50;   // 800
    const int K2 = OC  * 50;   // 1600

    // ws layout: y1 | y2 | M1 | M2 | Mf1 | Mf2 | csr | Ztail
    const size_t Y_BYTES   = (size_t)NV * NOUT * sizeof(float);     // 12.8 MB
    const size_t M1_BYTES  = (size_t)K1 * NOUT * sizeof(float);     // 512 KB
    const size_t M2_BYTES  = (size_t)K2 * NOUT * sizeof(float);     // 1 MB
    const size_t MF1_BYTES = (size_t)(K1 / 32) * 10 * 64 * 16;      // 256 KB
    const size_t MF2_BYTES = (size_t)(K2 / 32) * 10 * 64 * 16;      // 512 KB
    const size_t CSR_BYTES = (size_t)(2 * NV + NE) * sizeof(int);   // 800 KB
    char* ws = (char*)d_ws;
    float* y1 = (float*)(ws);
    float* y2 = (float*)(ws + Y_BYTES);
    float* M1 = (float*)(ws + 2 * Y_BYTES);
    float* M2 = (float*)(ws + 2 * Y_BYTES + M1_BYTES);
    uint32_t* Mf1 = (uint32_t*)(ws + 2 * Y_BYTES + M1_BYTES + M2_BYTES);
    uint32_t* Mf2 = (uint32_t*)(ws + 2 * Y_BYTES + M1_BYTES + M2_BYTES + MF1_BYTES);
    int* counts = (int*)(ws + 2 * Y_BYTES + M1_BYTES + M2_BYTES + MF1_BYTES + MF2_BYTES);
    int* cursor = counts + NV;
    int* order  = cursor + NV;
    size_t fixed = 2 * Y_BYTES + M1_BYTES + M2_BYTES + MF1_BYTES + MF2_BYTES
                 + CSR_BYTES;

    // Z buffer (bf16): ws tail if it has room, else d_out (dead until final_k)
    size_t tail = (ws_size > fixed) ? (ws_size - fixed) : 0;
    uint32_t* zbuf;
    size_t zcap;
    if (tail >= Y_BYTES) { zbuf = (uint32_t*)(ws + fixed); zcap = tail; }
    else                 { zbuf = (uint32_t*)d_out;        zcap = Y_BYTES; }
    int chunk1 = (int)(zcap / ((size_t)K1 * 2)); if (chunk1 > NV) chunk1 = NV;
    int chunk2 = (int)(zcap / ((size_t)K2 * 2)); if (chunk2 > NV) chunk2 = NV;

    hipMemsetAsync(counts, 0, NV * sizeof(int), stream);

    build_M<IC1><<<(K1 * NOUT + 255) / 256, 256, 0, stream>>>(W1, M1);
    build_M<OC> <<<(K2 * NOUT + 255) / 256, 256, 0, stream>>>(W2, M2);
    build_Mfrag<K1><<<((K1 / 32) * 2560 + 255) / 256, 256, 0, stream>>>(M1, Mf1);
    build_Mfrag<K2><<<((K2 / 32) * 2560 + 255) / 256, 256, 0, stream>>>(M2, Mf2);

    hist_k   <<<(NE + 255) / 256, 256, 0, stream>>>(ei, counts);
    scan_k   <<<1, 1024, 0, stream>>>(counts, cursor);
    scatter_k<<<(NE + 255) / 256, 256, 0, stream>>>(ei, cursor, order);

    // layer 1
    for (int v0 = 0; v0 < NV; v0 += chunk1) {
        int v1 = v0 + chunk1; if (v1 > NV) v1 = NV;
        int rows = v1 - v0;
        zbuild<IC1><<<(rows * IC1 + 255) / 256, 256, 0, stream>>>(
            x, ei, pre, conn, cursor, order, zbuf, v0, v1);
        gemm_mfma<K1><<<(rows + 63) / 64, 256, 0, stream>>>(
            zbuf, Mf1, y1 + (size_t)v0 * NOUT, rows);
    }
    relu_mid<<<(NV * 32 + 255) / 256, 256, 0, stream>>>(y1, b1);
    // layer 2
    for (int v0 = 0; v0 < NV; v0 += chunk2) {
        int v1 = v0 + chunk2; if (v1 > NV) v1 = NV;
        int rows = v1 - v0;
        zbuild<OC><<<(rows * OC + 255) / 256, 256, 0, stream>>>(
            y1, ei, pre, conn, cursor, order, zbuf, v0, v1);
        gemm_mfma<K2><<<(rows + 63) / 64, 256, 0, stream>>>(
            zbuf, Mf2, y2 + (size_t)v0 * NOUT, rows);
    }
    final_k<<<(NV * 32 + 255) / 256, 256, 0, stream>>>(y2, x, Wl, bl, b2, out);
}

// Round 13
// 270.897 us; speedup vs baseline: 1.2349x; 1.0335x over previous
//
#include <hip/hip_runtime.h>
#include <hip/hip_bf16.h>
#include <cstdint>

// ---------------------------------------------------------------------------
// GemResNetBlock: two gauge-equivariant convs + Fourier ReLU + linear residual
// Round-13: zbuild Z-store made line-coherent via LDS-staged transpose
// (round 12 counters: zbuild FETCH ~= Z size -> read-for-ownership on
//  partial-line 100B-stride stores was doubling zbuild's HBM traffic).
#define NV     20000
#define NE     160000
#define IC1    16
#define OC     32
#define DIN    5
#define NSLOT  49
#define NOUT   160              // (o,i) = 32*5
// ---------------------------------------------------------------------------
struct SlotTables {
    int n;
    int b[64], f[64], i[64], j[64];
    float v[64];
};

constexpr SlotTables make_slots() {
    SlotTables T{};
    float K[19][5][5][5] = {};   // [basis][freq][row i][col j]
    int nb = 0;
    const int BL = 2;
    auto add = [&](int f, const float (*cb)[2], const float (*sb)[2],
                   int m, int n) {
        if (f > BL) return;
        int r0 = (m == 0) ? 0 : (2 * m - 1), nr = (m == 0) ? 1 : 2;
        int c0 = (n == 0) ? 0 : (2 * n - 1), nc = (n == 0) ? 1 : 2;
        for (int a = 0; a < nr; a++)
            for (int bb = 0; bb < nc; bb++) {
                if (f == 0) {
                    K[nb][0][r0 + a][c0 + bb] = cb[a][bb];
                } else {
                    K[nb][2 * f - 1][r0 + a][c0 + bb] = cb[a][bb];
                    K[nb][2 * f    ][r0 + a][c0 + bb] = sb[a][bb];
                }
            }
        nb++;
    };
    const float ONE[2][2]  = {{1, 0}, {0, 0}};
    const float I2[2][2]   = {{1, 0}, {0, 1}};
    const float E2[2][2]   = {{0, -1}, {1, 0}};
    const float S2[2][2]   = {{1, 0}, {0, -1}};
    const float ES2[2][2]  = {{0, 1}, {1, 0}};
    const float NS2[2][2]  = {{-1, 0}, {0, 1}};
    const float C10[2][2]  = {{1, 0}, {0, 0}};
    const float C01[2][2]  = {{0, 0}, {1, 0}};
    const float CM10[2][2] = {{-1, 0}, {0, 0}};
    const float R10[2][2]  = {{1, 0}, {0, 0}};
    const float R01[2][2]  = {{0, 1}, {0, 0}};
    const float RM10[2][2] = {{-1, 0}, {0, 0}};

    for (int m = 0; m <= 2; m++)
        for (int n = 0; n <= 2; n++) {
            if (m == 0 && n == 0) {
                add(0, ONE, ONE, 0, 0);
            } else if (n == 0) {
                add(m, C10, C01, m, 0);
                add(m, C01, CM10, m, 0);
            } else if (m == 0) {
                add(n, R10, R01, 0, n);
                add(n, R01, RM10, 0, n);
            } else {
                int d = m - n;
                int f = d >= 0 ? d : -d;
                float sg = d >= 0 ? 1.f : -1.f;
                const float sgE[2][2]  = {{0, -sg}, {sg, 0}};
                const float msgI[2][2] = {{-sg, 0}, {0, -sg}};
                add(f, I2, sgE, m, n);
                add(f, E2, msgI, m, n);
                add(m + n, S2, ES2, m, n);
                add(m + n, ES2, NS2, m, n);
            }
        }
    T.n = 0;
    for (int i = 0; i < 5; i++)
        for (int b = 0; b < nb; b++)
            for (int f = 0; f < 5; f++)
                for (int j = 0; j < 5; j++)
                    if (K[b][f][i][j] != 0.0f) {
                        T.b[T.n] = b; T.f[T.n] = f; T.i[T.n] = i;
                        T.j[T.n] = j; T.v[T.n] = K[b][f][i][j];
                        T.n++;
                    }
    return T;
}

constexpr SlotTables SL = make_slots();
static_assert(SL.n == NSLOT, "expect 49 kernel-basis nonzeros");

__device__ __forceinline__ uint32_t bf16_rne(float f) {
    uint32_t u = __float_as_uint(f);
    u += 0x7fffu + ((u >> 16) & 1u);
    return u >> 16;
}

typedef __attribute__((ext_vector_type(8))) short bf16x8;   // MFMA A/B frag
typedef __attribute__((ext_vector_type(4))) float f32x4;    // MFMA C/D frag

// ---------------- M build: M[k][n], k=(c*50+j*10+q), n=(o*5+i) -------------
template<int C>
__global__ __launch_bounds__(256) void build_M(const float* __restrict__ W,
                                               float* __restrict__ M) {
    int t = blockIdx.x * 256 + threadIdx.x;
    const int K = C * 50;
    if (t >= K * NOUT) return;
    int n = t % NOUT, k = t / NOUT;
    int o = n / 5, i = n % 5;
    int c = k / 50, r50 = k % 50;
    int j = r50 / 10, q = r50 % 10;
    int f = q >> 1, r = q & 1;
    float acc = 0.f;
    #pragma unroll
    for (int s = 0; s < NSLOT; s++) {
        if (SL.j[s] == j && SL.f[s] == f && SL.i[s] == i)
            acc += SL.v[s] * W[(size_t)((SL.b[s] * 2 + r) * 32 + o) * C + c];
    }
    M[(size_t)k * NOUT + n] = acc;
}

// Swizzle M into MFMA B-fragment order (bf16):
// Mf[((ck*10+nt)*64+lane)*4+a] packs B[k0][col],B[k0+1][col]
// with k0 = ck*32 + (lane>>4)*8 + 2a, col = nt*16 + (lane&15).
template<int K>
__global__ __launch_bounds__(256) void build_Mfrag(const float* __restrict__ M,
                                                   uint32_t* __restrict__ Mf) {
    int t = blockIdx.x * 256 + threadIdx.x;
    const int total = (K / 32) * 10 * 64 * 4;
    if (t >= total) return;
    int a = t & 3;
    int idx = t >> 2;
    int lane = idx & 63; idx >>= 6;
    int nt = idx % 10;
    int ck = idx / 10;
    int col = nt * 16 + (lane & 15);
    int k0 = ck * 32 + (lane >> 4) * 8 + 2 * a;
    uint32_t lo = bf16_rne(M[(size_t)k0 * NOUT + col]);
    uint32_t hi = bf16_rne(M[(size_t)(k0 + 1) * NOUT + col]);
    Mf[t] = lo | (hi << 16);
}

// ---------------- CSR build ------------------------------------------------
__global__ __launch_bounds__(256) void hist_k(const int* __restrict__ ei,
                                              int* __restrict__ counts) {
    int e = blockIdx.x * 256 + threadIdx.x;
    if (e < NE) atomicAdd(&counts[ei[e]], 1);   // ei[e] = dst
}

__global__ __launch_bounds__(1024) void scan_k(const int* __restrict__ counts,
                                               int* __restrict__ cursor) {
    __shared__ int part[1024];
    int t = threadIdx.x;
    int base = t * 20;
    int local[20];
    int s = 0;
    #pragma unroll
    for (int k = 0; k < 20; k++) {
        int idx = base + k;
        int c = (idx < NV) ? counts[idx] : 0;
        local[k] = c; s += c;
    }
    part[t] = s;
    __syncthreads();
    for (int off = 1; off < 1024; off <<= 1) {
        int add = (t >= off) ? part[t - off] : 0;
        __syncthreads();
        part[t] += add;
        __syncthreads();
    }
    int run = (t == 0) ? 0 : part[t - 1];
    #pragma unroll
    for (int k = 0; k < 20; k++) {
        int idx = base + k;
        if (idx < NV) { cursor[idx] = run; run += local[k]; }
    }
}

__global__ __launch_bounds__(256) void scatter_k(const int* __restrict__ ei,
                                                 int* __restrict__ cursor,
                                                 int* __restrict__ order) {
    int e = blockIdx.x * 256 + threadIdx.x;
    if (e >= NE) return;
    int pos = atomicAdd(&cursor[ei[e]], 1);
    order[pos] = e;
}

// ---------------- Z build: thread (v,c) -> 50 bf16 (25 packed uints) -------
// Store goes through an LDS-staged block transpose so every global store
// instruction writes fully-covered, contiguous cache lines (round 12: the
// 100B-stride per-thread stores caused ~Z-sized RMW FETCH from HBM).
template<int C>
__global__ __launch_bounds__(256) void zbuild(const float* __restrict__ xin,
                                              const int*   __restrict__ ei,
                                              const float* __restrict__ pre,
                                              const float* __restrict__ conn,
                                              const int* __restrict__ cursor,
                                              const int* __restrict__ order,
                                              uint32_t* __restrict__ Z,
                                              int v0, int v1) {
    __shared__ uint32_t st[6400];        // 256 rows x 25 uints = 25.6 KB
    int tid = threadIdx.x;
    int t = blockIdx.x * 256 + tid;
    int rows = (v1 - v0) * C;
    bool valid = (t < rows);
    int c = t % C;
    int v = v0 + t / C;
    int beg = 0, end = 0;
    if (valid) { beg = (v == 0) ? 0 : cursor[v - 1]; end = cursor[v]; }
    float acc[50];
    #pragma unroll
    for (int z = 0; z < 50; z++) acc[z] = 0.f;

    for (int k = beg; k < end; k++) {
        int e = order[k];
        int src = ei[NE + e];
        float al = conn[e];
        float c1 = __cosf(al), s1 = __sinf(al);
        float c2 = c1 * c1 - s1 * s1, s2 = 2.0f * c1 * s1;
        float p[10];
        #pragma unroll
        for (int q = 0; q < 10; q++) p[q] = pre[(size_t)e * 10 + q];
        const float* xb = xin + ((size_t)src * C + c) * DIN;
        float x0 = xb[0], x1 = xb[1], x2 = xb[2], x3 = xb[3], x4 = xb[4];
        float xt[5];
        xt[0] = x0;
        xt[1] = c1 * x1 - s1 * x2;
        xt[2] = s1 * x1 + c1 * x2;
        xt[3] = c2 * x3 - s2 * x4;
        xt[4] = s2 * x3 + c2 * x4;
        #pragma unroll
        for (int j = 0; j < 5; j++)
            #pragma unroll
            for (int q = 0; q < 10; q++)
                acc[j * 10 + q] = fmaf(xt[j], p[q], acc[j * 10 + q]);
    }
    // stage 25 packed uints into LDS (stride 25: odd -> 2-way alias, free)
    uint32_t* sb = st + tid * 25;
    #pragma unroll
    for (int z = 0; z < 25; z++)
        sb[z] = bf16_rne(acc[2 * z]) | (bf16_rne(acc[2 * z + 1]) << 16);
    __syncthreads();
    // linear block writeout: each store inst covers 1KB of contiguous lines
    size_t gbase = (size_t)blockIdx.x * 6400;
    int rbase = blockIdx.x * 256;
    for (int i = tid; i < 6400; i += 256) {
        if (rbase + i / 25 < rows) Z[gbase + i] = st[i];
    }
}

// ---------------- MFMA GEMM: Y[v,n] = sum_k Z[v,k]*M[k,n] ------------------
// 4 waves/block, 64 rows/block, all 160 cols.  B-frags (identical for the 4
// waves) live in double-buffered LDS, filled by async DMA (global_load_lds,
// width 16): per chunk, stage chunk ck+1 into Bs[buf^1] BEFORE computing ck,
// prefetch A one chunk ahead in regs, one __syncthreads per chunk.
template<int K>
__global__ __launch_bounds__(256) void gemm_mfma(const uint32_t* __restrict__ Z,
                                                 const uint32_t* __restrict__ Mf,
                                                 float* __restrict__ Y,
                                                 int rows) {
    constexpr int NC = K / 32;
    __shared__ uint4 Bs[2][640];        // 2 x 10 KB
    int t = threadIdx.x;
    int lane = t & 63;
    int wave = t >> 6;
    int r0 = blockIdx.x * 64 + wave * 16;
    int mrow = lane & 15;
    int q = lane >> 4;
    int ra = r0 + mrow;
    if (ra >= rows) ra = rows - 1;          // clamp A loads; store masked
    const uint32_t* za = Z + (size_t)ra * (K / 2) + q * 4;
    const uint4* mfg = (const uint4*)Mf + lane;

    auto stage = [&](int ck, int nb) {
        const uint4* gp = mfg + (size_t)ck * 640;
        for (int i = wave; i < 10; i += 4)
            __builtin_amdgcn_global_load_lds(
                (const __attribute__((address_space(1))) void*)(gp + i * 64),
                (__attribute__((address_space(3))) void*)(&Bs[nb][i * 64]),
                16, 0, 0);
    };

    f32x4 acc[10];
    #pragma unroll
    for (int nt = 0; nt < 10; nt++) acc[nt] = {0.f, 0.f, 0.f, 0.f};

    stage(0, 0);
    bf16x8 af = *(const bf16x8*)za;         // A chunk 0 (overlaps DMA wait)
    __syncthreads();

    for (int ck = 0; ck < NC; ck++) {
        int buf = ck & 1;
        bf16x8 af_n = af;
        if (ck + 1 < NC) {
            stage(ck + 1, buf ^ 1);         // async DMA, consumed next iter
            af_n = *(const bf16x8*)(za + (ck + 1) * 16);
        }
        bf16x8 bf[10];
        #pragma unroll
        for (int nt = 0; nt < 10; nt++)
            bf[nt] = *(const bf16x8*)&Bs[buf][nt * 64 + lane];
        #pragma unroll
        for (int nt = 0; nt < 10; nt++)
            acc[nt] = __builtin_amdgcn_mfma_f32_16x16x32_bf16(af, bf[nt],
                                                              acc[nt], 0, 0, 0);
        af = af_n;
        __syncthreads();                    // drain DMA + protect Bs[buf]
    }
    // C/D layout: col = lane&15, row = q*4 + reg  [verified m89/m91]
    #pragma unroll
    for (int reg = 0; reg < 4; reg++) {
        int rr = r0 + q * 4 + reg;
        if (rr < rows) {
            float* yb = Y + (size_t)rr * NOUT + (lane & 15);
            #pragma unroll
            for (int nt = 0; nt < 10; nt++) yb[nt * 16] = acc[nt][reg];
        }
    }
}

// ---------------- Fourier ReLU + epilogues ---------------------------------
__device__ __forceinline__ void fourier_relu(float d0, float d1, float d2,
                                             float d3, float d4, float* out5) {
    float o0 = 0, o1 = 0, o2 = 0, o3 = 0, o4 = 0;
    #pragma unroll
    for (int k = 0; k < 7; k++) {
        float th = (float)k * (6.28318530717958647692f / 7.0f);
        float ck = __cosf(th), sk = __sinf(th);
        float c2k = ck * ck - sk * sk, s2k = 2.f * ck * sk;
        float sv = d0 + ck * d1 + sk * d2 + c2k * d3 + s2k * d4;
        sv = fmaxf(sv, 0.f);
        o0 += sv; o1 += sv * ck; o2 += sv * sk; o3 += sv * c2k; o4 += sv * s2k;
    }
    const float i7 = 1.0f / 7.0f;
    out5[0] = o0 * i7; out5[1] = o1 * (2.f * i7); out5[2] = o2 * (2.f * i7);
    out5[3] = o3 * (2.f * i7); out5[4] = o4 * (2.f * i7);
}

__global__ __launch_bounds__(256) void relu_mid(float* __restrict__ y,
                                                const float* __restrict__ b1) {
    int t = blockIdx.x * 256 + threadIdx.x;     // v*32 + ch
    if (t >= NV * 32) return;
    int ch = t & 31;
    float* yb = y + (size_t)t * 5;
    float r[5];
    fourier_relu(yb[0] + b1[ch], yb[1], yb[2], yb[3], yb[4], r);
    #pragma unroll
    for (int d = 0; d < 5; d++) yb[d] = r[d];
}

__global__ __launch_bounds__(256) void final_k(const float* __restrict__ y2,
                                               const float* __restrict__ x,
                                               const float* __restrict__ Wl,
                                               const float* __restrict__ bl,
                                               const float* __restrict__ b2,
                                               float* __restrict__ out) {
    int t = blockIdx.x * 256 + threadIdx.x;     // v*32 + o
    if (t >= NV * 32) return;
    int o = t & 31;
    int v = t >> 5;
    float r0 = 0, r1 = 0, r2 = 0, r3 = 0, r4 = 0;
    const float* xb = x + (size_t)v * (IC1 * DIN);
    const float* wl = Wl + o * IC1;
    #pragma unroll
    for (int c = 0; c < IC1; c++) {
        float w = wl[c];
        r0 = fmaf(w, xb[c*5+0], r0); r1 = fmaf(w, xb[c*5+1], r1);
        r2 = fmaf(w, xb[c*5+2], r2); r3 = fmaf(w, xb[c*5+3], r3);
        r4 = fmaf(w, xb[c*5+4], r4);
    }
    float blo = bl[o];
    const float* yb = y2 + (size_t)t * 5;
    float d0 = yb[0] + b2[o] + r0 + blo;
    float d1 = yb[1] + r1 + blo;
    float d2 = yb[2] + r2 + blo;
    float d3 = yb[3] + r3 + blo;
    float d4 = yb[4] + r4 + blo;
    float r[5];
    fourier_relu(d0, d1, d2, d3, d4, r);
    float* ob = out + (size_t)t * 5;
    #pragma unroll
    for (int d = 0; d < 5; d++) ob[d] = r[d];
}

extern "C" void kernel_launch(void* const* d_in, const int* in_sizes, int n_in,
                              void* d_out, int out_size, void* d_ws, size_t ws_size,
                              hipStream_t stream) {
    const float* x    = (const float*)d_in[0];
    const int*   ei   = (const int*)  d_in[1];
    const float* pre  = (const float*)d_in[2];
    const float* conn = (const float*)d_in[3];
    const float* W1   = (const float*)d_in[4];
    const float* b1   = (const float*)d_in[5];
    const float* W2   = (const float*)d_in[6];
    const float* b2   = (const float*)d_in[7];
    const float* Wl   = (const float*)d_in[8];
    const float* bl   = (const float*)d_in[9];
    float* out = (float*)d_out;

    const int K1 = IC1 * 50;   // 800
    const int K2 = OC  * 50;   // 1600

    // ws layout: y1 | y2 | M1 | M2 | Mf1 | Mf2 | csr | Ztail
    const size_t Y_BYTES   = (size_t)NV * NOUT * sizeof(float);     // 12.8 MB
    const size_t M1_BYTES  = (size_t)K1 * NOUT * sizeof(float);     // 512 KB
    const size_t M2_BYTES  = (size_t)K2 * NOUT * sizeof(float);     // 1 MB
    const size_t MF1_BYTES = (size_t)(K1 / 32) * 10 * 64 * 16;      // 256 KB
    const size_t MF2_BYTES = (size_t)(K2 / 32) * 10 * 64 * 16;      // 512 KB
    const size_t CSR_BYTES = (size_t)(2 * NV + NE) * sizeof(int);   // 800 KB
    char* ws = (char*)d_ws;
    float* y1 = (float*)(ws);
    float* y2 = (float*)(ws + Y_BYTES);
    float* M1 = (float*)(ws + 2 * Y_BYTES);
    float* M2 = (float*)(ws + 2 * Y_BYTES + M1_BYTES);
    uint32_t* Mf1 = (uint32_t*)(ws + 2 * Y_BYTES + M1_BYTES + M2_BYTES);
    uint32_t* Mf2 = (uint32_t*)(ws + 2 * Y_BYTES + M1_BYTES + M2_BYTES + MF1_BYTES);
    int* counts = (int*)(ws + 2 * Y_BYTES + M1_BYTES + M2_BYTES + MF1_BYTES + MF2_BYTES);
    int* cursor = counts + NV;
    int* order  = cursor + NV;
    size_t fixed = 2 * Y_BYTES + M1_BYTES + M2_BYTES + MF1_BYTES + MF2_BYTES
                 + CSR_BYTES;

    // Z buffer (bf16): ws tail if it has room, else d_out (dead until final_k)
    size_t tail = (ws_size > fixed) ? (ws_size - fixed) : 0;
    uint32_t* zbuf;
    size_t zcap;
    if (tail >= Y_BYTES) { zbuf = (uint32_t*)(ws + fixed); zcap = tail; }
    else                 { zbuf = (uint32_t*)d_out;        zcap = Y_BYTES; }
    int chunk1 = (int)(zcap / ((size_t)K1 * 2)); if (chunk1 > NV) chunk1 = NV;
    int chunk2 = (int)(zcap / ((size_t)K2 * 2)); if (chunk2 > NV) chunk2 = NV;

    hipMemsetAsync(counts, 0, NV * sizeof(int), stream);

    build_M<IC1><<<(K1 * NOUT + 255) / 256, 256, 0, stream>>>(W1, M1);
    build_M<OC> <<<(K2 * NOUT + 255) / 256, 256, 0, stream>>>(W2, M2);
    build_Mfrag<K1><<<((K1 / 32) * 2560 + 255) / 256, 256, 0, stream>>>(M1, Mf1);
    build_Mfrag<K2><<<((K2 / 32) * 2560 + 255) / 256, 256, 0, stream>>>(M2, Mf2);

    hist_k   <<<(NE + 255) / 256, 256, 0, stream>>>(ei, counts);
    scan_k   <<<1, 1024, 0, stream>>>(counts, cursor);
    scatter_k<<<(NE + 255) / 256, 256, 0, stream>>>(ei, cursor, order);

    // layer 1
    for (int v0 = 0; v0 < NV; v0 += chunk1) {
        int v1 = v0 + chunk1; if (v1 > NV) v1 = NV;
        int rows = v1 - v0;
        zbuild<IC1><<<(rows * IC1 + 255) / 256, 256, 0, stream>>>(
            x, ei, pre, conn, cursor, order, zbuf, v0, v1);
        gemm_mfma<K1><<<(rows + 63) / 64, 256, 0, stream>>>(
            zbuf, Mf1, y1 + (size_t)v0 * NOUT, rows);
    }
    relu_mid<<<(NV * 32 + 255) / 256, 256, 0, stream>>>(y1, b1);
    // layer 2
    for (int v0 = 0; v0 < NV; v0 += chunk2) {
        int v1 = v0 + chunk2; if (v1 > NV) v1 = NV;
        int rows = v1 - v0;
        zbuild<OC><<<(rows * OC + 255) / 256, 256, 0, stream>>>(
            y1, ei, pre, conn, cursor, order, zbuf, v0, v1);
        gemm_mfma<K2><<<(rows + 63) / 64, 256, 0, stream>>>(
            zbuf, Mf2, y2 + (size_t)v0 * NOUT, rows);
    }
    final_k<<<(NV * 32 + 255) / 256, 256, 0, stream>>>(y2, x, Wl, bl, b2, out);
}